// Round 7
// baseline (352.556 us; speedup 1.0000x reference)
//
#include <hip/hip_runtime.h>

#define OBS_T 20
#define HID 128
#define NGATE 512
#define MB 16          // batch rows per tile
#define HSTR 136       // hbuf row stride in bf16 (272B = 17*16B)
#define PBLK 512       // persistent grid size (2 blocks/CU on 256 CUs)

typedef __bf16 bf16x8 __attribute__((ext_vector_type(8)));
typedef __bf16 bf16x4 __attribute__((ext_vector_type(4)));
typedef float f32x4 __attribute__((ext_vector_type(4)));
typedef float f32x2 __attribute__((ext_vector_type(2)));

__device__ __forceinline__ float fast_rcp(float x) { return __builtin_amdgcn_rcpf(x); }
#if __has_builtin(__builtin_amdgcn_exp2f)
__device__ __forceinline__ float exp2_hw(float x) { return __builtin_amdgcn_exp2f(x); }
#else
__device__ __forceinline__ float exp2_hw(float x) { return __expf(x * 0.69314718056f); }
#endif
#define LOG2E 1.442695041f

// gate scale: preacts arrive PRE-SCALED by s_q so exp2 needs no mul.
// s_q = -LOG2E for i,f,o ; -2*LOG2E for g (since tanh uses e^{-2x})
__device__ __host__ __forceinline__ float gate_scale(int q) {
  return (q == 2) ? (-2.0f * LOG2E) : (-LOG2E);
}

// ---- prep 1: fold embedding into rank-2 + bias, gate-major permutation ----
// gate row r = q*128 + j (torch i,f,g,o). np = (j>>4)*64 + q*16 + (j&15)
// Tables written as DUPLICATED f32x2 pairs {v,v} so the main kernel's packed
// acc-init reads them as 64-bit operands with NO splat movs (R6-proven).
__global__ void prep_vec(const float* __restrict__ W_emb, const float* __restrict__ b_emb,
                         const float* __restrict__ W_ih, const float* __restrict__ b_ih,
                         const float* __restrict__ b_hh, float2* __restrict__ wxb) {
  int r = blockIdx.x * blockDim.x + threadIdx.x;
  if (r >= NGATE) return;
  float s0 = 0.f, s1 = 0.f, sb = 0.f;
  for (int d = 0; d < 64; ++d) {
    float w = W_ih[r * 64 + d];
    s0 += w * W_emb[d * 2 + 0];
    s1 += w * W_emb[d * 2 + 1];
    sb += w * b_emb[d];
  }
  int q = r >> 7, j = r & 127;
  float sc = gate_scale(q);
  int np = (j >> 4) * 64 + q * 16 + (j & 15);
  float w0 = s0 * sc, w1 = s1 * sc, bb = (b_ih[r] + b_hh[r] + sb) * sc;
  wxb[0 * NGATE + np] = make_float2(w0, w0);
  wxb[1 * NGATE + np] = make_float2(w1, w1);
  wxb[2 * NGATE + np] = make_float2(bb, bb);
}

// ---- prep 2: W_hh -> bf16 B-fragments (r6/r8/r10 mapping), PRE-SCALED ----
__global__ void prep_wp(const float* __restrict__ W_hh, __bf16* __restrict__ Wp) {
  int tid = blockIdx.x * blockDim.x + threadIdx.x;  // 0..65535
  int jj = tid & 7;
  int lane = (tid >> 3) & 63;
  int frag = tid >> 9;  // 0..127
  int ks = frag & 3;
  int q = (frag >> 2) & 3;
  int g16 = frag >> 4;
  int cn = lane & 15, quad = lane >> 4;
  int r = q * 128 + g16 * 16 + cn;
  int k = ks * 32 + quad * 8 + jj;
  Wp[tid] = (__bf16)(W_hh[r * 128 + k] * gate_scale(q));
}

// ---- packed (f32x2) helpers: scalar transcendentals, VOP3P-packable arith ----
__device__ __forceinline__ f32x2 exp2_2(f32x2 v) {
  f32x2 r;
  r.x = exp2_hw(v.x);
  r.y = exp2_hw(v.y);
  return r;
}
__device__ __forceinline__ f32x2 rcp_2(f32x2 v) {
  f32x2 r;
  r.x = fast_rcp(v.x);
  r.y = fast_rcp(v.y);
  return r;
}

// lane-local LSTM cell on PRE-SCALED preacts, PAIRED over two adjacent
// accumulator rows (acc[q].xy / .zw — natural even-aligned VGPR pairs from
// the MFMA C-layout). Same math as the scalar chain (absmax 1.95e-3,
// R2/R3/R6-verified packed).
__device__ __forceinline__ f32x2 cell_update_pk(f32x2 gi, f32x2 gf, f32x2 gg,
                                                f32x2 go, f32x2& c) {
  f32x2 e_i = exp2_2(gi);
  f32x2 e_f = exp2_2(gf);
  f32x2 e_g = exp2_2(gg);
  f32x2 e_o = exp2_2(go);
  f32x2 a_i = e_i + 1.f;
  f32x2 a_f = e_f + 1.f;
  f32x2 a_g = e_g + 1.f;
  f32x2 bg = 1.f - e_g;  // == 2 - a_g
  f32x2 m1 = a_i * a_g;
  f32x2 r = rcp_2(m1 * a_f);
  f32x2 t = c * m1 + bg * a_f;  // contracts to v_pk_fma
  c = t * r;
  f32x2 e_c = exp2_2(c * (-2.f * LOG2E));
  f32x2 a_c = e_c + 1.f;
  f32x2 bc = 1.f - e_c;  // == 2 - a_c
  return bc * rcp_2((e_o + 1.f) * a_c);
}

// Packed acc-init from duplicated-pair LDS tables (R6-proven VALU cut).
// R7: placed POST-barrier again — R6's pre-barrier "shadow" placement put
// these 16 ds_reads inside __syncthreads' lgkmcnt(0) drain, delaying every
// wave's barrier entry by the LDS read latency. Post-barrier they overlap
// with the A-frag read latency instead.
#define ACC_INIT(T)                                                            \
  do {                                                                         \
    f32x2 x01 = *(const f32x2*)&obs_sx[(T)][quad * 4];                         \
    f32x2 x23 = *(const f32x2*)&obs_sx[(T)][quad * 4 + 2];                     \
    f32x2 y01 = *(const f32x2*)&obs_sy[(T)][quad * 4];                         \
    f32x2 y23 = *(const f32x2*)&obs_sy[(T)][quad * 4 + 2];                     \
    _Pragma("unroll") for (int q = 0; q < 4; ++q) {                            \
      const int n = wv * 64 + q * 16 + cn;                                     \
      f32x2 w0 = *(const f32x2*)&wxb_s[0][n][0];                               \
      f32x2 w1 = *(const f32x2*)&wxb_s[1][n][0];                               \
      f32x2 b2 = *(const f32x2*)&wxb_s[2][n][0];                               \
      f32x2 lo = y01 * w1 + (x01 * w0 + b2);                                   \
      f32x2 hi = y23 * w1 + (x23 * w0 + b2);                                   \
      acc[q].x = lo.x;                                                         \
      acc[q].y = lo.y;                                                         \
      acc[q].z = hi.x;                                                         \
      acc[q].w = hi.y;                                                         \
    }                                                                          \
  } while (0)

// ---- main fused LSTM, R7: PERSISTENT blocks + post-barrier init ----
// 512 threads = 8 waves, wave wv owns ONE unit-group; grid = 512 blocks =
// 2 blocks/CU = 4 waves/SIMD (R3/R5 PROVEN: 2 co-resident blocks with
// independent barriers is load-bearing). Each block loops over
// ntiles/gridDim tiles (8 at batch 65536), staging Bf fragments and the
// 12 KB wxb table ONCE instead of once per generation — amortizes 7/8 of
// the prologue that the 8 short-lived generations re-paid.
// Ledger (R1/R4 lesson — Bf is AGPR, invisible to VGPR_Count): arch ~60 +
// 64 AGPR ≈ 124 <= 128 unified cap at 4 waves/SIMD.
// Tripwires: WRITE_SIZE exactly 32768 KB, FETCH ~37 MB, VGPR_Count <= 64.
__global__ __launch_bounds__(512, 4) void lstm_fused(
    const float* __restrict__ obs, const float* __restrict__ h0,
    const float* __restrict__ c0, const __bf16* __restrict__ Wp,
    const float* __restrict__ wxbp, float* __restrict__ out, int batch) {
  __shared__ __align__(16) __bf16 hbuf[2][MB][HSTR];
  __shared__ __align__(16) float obs_sx[OBS_T][MB];
  __shared__ __align__(16) float obs_sy[OBS_T][MB];
  __shared__ __align__(16) float wxb_s[3][NGATE][2];  // duplicated pairs

  const int tid = threadIdx.x;
  const int lane = tid & 63;
  const int wv = tid >> 6;  // 0..7 — unit-group index
  const int cn = lane & 15;
  const int quad = lane >> 4;
  const int ju = wv * 16 + cn;  // this wave's output column

  // ---- once-per-block staging ----
  // duplicated wxb tables: 3 x 4 KB = 768 float4
  for (int i = tid; i < 768; i += 512)
    ((float4*)wxb_s)[i] = ((const float4*)wxbp)[i];
  // persistent B fragments: 1 unit-group x 4 gates x 4 ksteps = 64 regs (AGPR)
  bf16x8 Bf[4][4];  // [ks][q]
  {
    const bf16x8* wp8 = (const bf16x8*)Wp;
#pragma unroll
    for (int q = 0; q < 4; ++q)
#pragma unroll
      for (int ks = 0; ks < 4; ++ks)
        Bf[ks][q] = wp8[(wv * 16 + q * 4 + ks) * 64 + lane];
  }

  const int ntiles = batch / MB;
  const int tpb = ntiles / gridDim.x;  // tiles per block (8 at batch 65536)

#pragma unroll 1
  for (int tt = 0; tt < tpb; ++tt) {
    const int bbase = (blockIdx.x * tpb + tt) * MB;

    // ---- per-tile staging (previous tile's trailing barrier protects LDS)
    // obs tile SoA: 320 float2 loads
    if (tid < OBS_T * MB) {
      const int t = tid >> 4, row = tid & 15;
      float2 v = ((const float2*)obs)[t * batch + bbase + row];
      obs_sx[t][row] = v.x;
      obs_sy[t][row] = v.y;
    }
    // h0 tile fp32 -> bf16 LDS: 16 rows x 32 float4 = 512, one per thread
    {
      int row = tid >> 5, c4 = tid & 31;
      float4 v = ((const float4*)h0)[(bbase + row) * 32 + c4];
      bf16x4 b;
      b.x = (__bf16)v.x; b.y = (__bf16)v.y; b.z = (__bf16)v.z; b.w = (__bf16)v.w;
      *(bf16x4*)&hbuf[0][row][c4 * 4] = b;
    }
    // c state as f32x2 pairs: cc2[p] = c for rows (quad*4+2p, quad*4+2p+1)
    f32x2 cc2[2];
#pragma unroll
    for (int p = 0; p < 2; ++p) {
      cc2[p].x = c0[(bbase + quad * 4 + 2 * p + 0) * HID + ju];
      cc2[p].y = c0[(bbase + quad * 4 + 2 * p + 1) * HID + ju];
    }

    __syncthreads();

    f32x4 acc[4];  // [q]
    int cur = 0;
#pragma unroll 1
    for (int t = 0; t < OBS_T - 1; ++t) {
      // acc-init post-barrier (overlaps A-frag read latency)
      ACC_INIT(t);

      // gates += h @ (scaled W_hh)^T : ONE A-load per ks, 16 MFMAs
#pragma unroll
      for (int ks = 0; ks < 4; ++ks) {
        bf16x8 Av = *(const bf16x8*)&hbuf[cur][cn][ks * 32 + quad * 8];
#pragma unroll
        for (int q = 0; q < 4; ++q)
          acc[q] = __builtin_amdgcn_mfma_f32_16x16x32_bf16(Av, Bf[ks][q], acc[q], 0, 0, 0);
      }

      // 4 cell updates as 2 packed pair-updates (natural .xy/.zw pairs)
      const int nxt = cur ^ 1;
      {
        f32x2 hlo = cell_update_pk(acc[0].xy, acc[1].xy, acc[2].xy, acc[3].xy, cc2[0]);
        f32x2 hhi = cell_update_pk(acc[0].zw, acc[1].zw, acc[2].zw, acc[3].zw, cc2[1]);
        hbuf[nxt][quad * 4 + 0][ju] = (__bf16)hlo.x;
        hbuf[nxt][quad * 4 + 1][ju] = (__bf16)hlo.y;
        hbuf[nxt][quad * 4 + 2][ju] = (__bf16)hhi.x;
        hbuf[nxt][quad * 4 + 3][ju] = (__bf16)hhi.y;
      }
      __syncthreads();
      cur = nxt;
    }

    // peeled final step (t=19): h straight to global
    {
      ACC_INIT(OBS_T - 1);
#pragma unroll
      for (int ks = 0; ks < 4; ++ks) {
        bf16x8 Av = *(const bf16x8*)&hbuf[cur][cn][ks * 32 + quad * 8];
#pragma unroll
        for (int q = 0; q < 4; ++q)
          acc[q] = __builtin_amdgcn_mfma_f32_16x16x32_bf16(Av, Bf[ks][q], acc[q], 0, 0, 0);
      }
      f32x2 hlo = cell_update_pk(acc[0].xy, acc[1].xy, acc[2].xy, acc[3].xy, cc2[0]);
      f32x2 hhi = cell_update_pk(acc[0].zw, acc[1].zw, acc[2].zw, acc[3].zw, cc2[1]);
      out[(bbase + quad * 4 + 0) * HID + ju] = hlo.x;
      out[(bbase + quad * 4 + 1) * HID + ju] = hlo.y;
      out[(bbase + quad * 4 + 2) * HID + ju] = hhi.x;
      out[(bbase + quad * 4 + 3) * HID + ju] = hhi.y;
    }
    // protect LDS (obs_s / hbuf) before next tile's staging overwrites it
    __syncthreads();
  }
}

extern "C" void kernel_launch(void* const* d_in, const int* in_sizes, int n_in,
                              void* d_out, int out_size, void* d_ws, size_t ws_size,
                              hipStream_t stream) {
  const float* obs = (const float*)d_in[0];
  const float* h0 = (const float*)d_in[1];
  const float* c0 = (const float*)d_in[2];
  const float* W_emb = (const float*)d_in[3];
  const float* b_emb = (const float*)d_in[4];
  const float* W_ih = (const float*)d_in[5];
  const float* W_hh = (const float*)d_in[6];
  const float* b_ih = (const float*)d_in[7];
  const float* b_hh = (const float*)d_in[8];
  float* out = (float*)d_out;
  const int batch = in_sizes[1] / HID;

  __bf16* Wp = (__bf16*)d_ws;                      // 65536 bf16 = 128 KB
  float2* wxb = (float2*)((char*)d_ws + 131072);   // 3 x 512 duplicated f32 pairs = 12 KB

  prep_vec<<<2, 256, 0, stream>>>(W_emb, b_emb, W_ih, b_ih, b_hh, wxb);
  prep_wp<<<256, 256, 0, stream>>>(W_hh, Wp);

  const int ntiles = batch / MB;
  const int nblk = (ntiles % PBLK == 0) ? PBLK : ntiles;  // persistent grid
  lstm_fused<<<nblk, 512, 0, stream>>>(obs, h0, c0, Wp, (const float*)wxb, out, batch);
}

// Round 8
// 336.952 us; speedup vs baseline: 1.0463x; 1.0463x over previous
//
#include <hip/hip_runtime.h>

#define OBS_T 20
#define HID 128
#define NGATE 512
#define MB 16          // batch rows per block
#define HSTR 136       // hbuf row stride in bf16 (272B = 17*16B)

typedef __bf16 bf16x8 __attribute__((ext_vector_type(8)));
typedef __bf16 bf16x4 __attribute__((ext_vector_type(4)));
typedef float f32x4 __attribute__((ext_vector_type(4)));
typedef float f32x2 __attribute__((ext_vector_type(2)));

__device__ __forceinline__ float fast_rcp(float x) { return __builtin_amdgcn_rcpf(x); }
#if __has_builtin(__builtin_amdgcn_exp2f)
__device__ __forceinline__ float exp2_hw(float x) { return __builtin_amdgcn_exp2f(x); }
#else
__device__ __forceinline__ float exp2_hw(float x) { return __expf(x * 0.69314718056f); }
#endif
#define LOG2E 1.442695041f

// gate scale: preacts arrive PRE-SCALED by s_q so exp2 needs no mul.
// s_q = -LOG2E for i,f,o ; -2*LOG2E for g (since tanh uses e^{-2x})
__device__ __host__ __forceinline__ float gate_scale(int q) {
  return (q == 2) ? (-2.0f * LOG2E) : (-LOG2E);
}

// ---- prep 1: fold embedding into rank-2 + bias, gate-major permutation ----
// gate row r = q*128 + j (torch i,f,g,o). np = (j>>4)*64 + q*16 + (j&15)
// Tables written as DUPLICATED f32x2 pairs {v,v} so the main kernel's packed
// acc-init reads them as 64-bit operands with NO splat movs (R6-proven).
__global__ void prep_vec(const float* __restrict__ W_emb, const float* __restrict__ b_emb,
                         const float* __restrict__ W_ih, const float* __restrict__ b_ih,
                         const float* __restrict__ b_hh, float2* __restrict__ wxb) {
  int r = blockIdx.x * blockDim.x + threadIdx.x;
  if (r >= NGATE) return;
  float s0 = 0.f, s1 = 0.f, sb = 0.f;
  for (int d = 0; d < 64; ++d) {
    float w = W_ih[r * 64 + d];
    s0 += w * W_emb[d * 2 + 0];
    s1 += w * W_emb[d * 2 + 1];
    sb += w * b_emb[d];
  }
  int q = r >> 7, j = r & 127;
  float sc = gate_scale(q);
  int np = (j >> 4) * 64 + q * 16 + (j & 15);
  float w0 = s0 * sc, w1 = s1 * sc, bb = (b_ih[r] + b_hh[r] + sb) * sc;
  wxb[0 * NGATE + np] = make_float2(w0, w0);
  wxb[1 * NGATE + np] = make_float2(w1, w1);
  wxb[2 * NGATE + np] = make_float2(bb, bb);
}

// ---- prep 2: W_hh -> bf16 B-fragments (r6/r8/r10 mapping), PRE-SCALED ----
__global__ void prep_wp(const float* __restrict__ W_hh, __bf16* __restrict__ Wp) {
  int tid = blockIdx.x * blockDim.x + threadIdx.x;  // 0..65535
  int jj = tid & 7;
  int lane = (tid >> 3) & 63;
  int frag = tid >> 9;  // 0..127
  int ks = frag & 3;
  int q = (frag >> 2) & 3;
  int g16 = frag >> 4;
  int cn = lane & 15, quad = lane >> 4;
  int r = q * 128 + g16 * 16 + cn;
  int k = ks * 32 + quad * 8 + jj;
  Wp[tid] = (__bf16)(W_hh[r * 128 + k] * gate_scale(q));
}

// ---- packed (f32x2) helpers: scalar transcendentals, VOP3P-packable arith ----
__device__ __forceinline__ f32x2 exp2_2(f32x2 v) {
  f32x2 r;
  r.x = exp2_hw(v.x);
  r.y = exp2_hw(v.y);
  return r;
}
__device__ __forceinline__ f32x2 rcp_2(f32x2 v) {
  f32x2 r;
  r.x = fast_rcp(v.x);
  r.y = fast_rcp(v.y);
  return r;
}

// lane-local LSTM cell on PRE-SCALED preacts, PAIRED over two adjacent
// accumulator rows (acc[q].xy / .zw — natural even-aligned VGPR pairs from
// the MFMA C-layout). Same math as the scalar chain (absmax 1.95e-3,
// R2/R3/R6-verified packed).
__device__ __forceinline__ f32x2 cell_update_pk(f32x2 gi, f32x2 gf, f32x2 gg,
                                                f32x2 go, f32x2& c) {
  f32x2 e_i = exp2_2(gi);
  f32x2 e_f = exp2_2(gf);
  f32x2 e_g = exp2_2(gg);
  f32x2 e_o = exp2_2(go);
  f32x2 a_i = e_i + 1.f;
  f32x2 a_f = e_f + 1.f;
  f32x2 a_g = e_g + 1.f;
  f32x2 bg = 1.f - e_g;  // == 2 - a_g
  f32x2 m1 = a_i * a_g;
  f32x2 r = rcp_2(m1 * a_f);
  f32x2 t = c * m1 + bg * a_f;  // contracts to v_pk_fma
  c = t * r;
  f32x2 e_c = exp2_2(c * (-2.f * LOG2E));
  f32x2 a_c = e_c + 1.f;
  f32x2 bc = 1.f - e_c;  // == 2 - a_c
  return bc * rcp_2((e_o + 1.f) * a_c);
}

// Packed acc-init from duplicated-pair LDS tables (R6-proven VALU cut:
// VALUBusy 61->57 at equal occupancy). R8: placed at R3's ORIGINAL position
// — top of the loop body, post-barrier — where its 16 ds_reads overlap the
// A-frag read latency. R6's pre-barrier "shadow" placement put them inside
// __syncthreads' lgkmcnt(0) drain (every wave's barrier entry waited on
// them); R7's post-barrier test was confounded by the persistent-loop
// regression. This round isolates diet + placement in the fast launch.
#define ACC_INIT(T)                                                            \
  do {                                                                         \
    f32x2 x01 = *(const f32x2*)&obs_sx[(T)][quad * 4];                         \
    f32x2 x23 = *(const f32x2*)&obs_sx[(T)][quad * 4 + 2];                     \
    f32x2 y01 = *(const f32x2*)&obs_sy[(T)][quad * 4];                         \
    f32x2 y23 = *(const f32x2*)&obs_sy[(T)][quad * 4 + 2];                     \
    _Pragma("unroll") for (int q = 0; q < 4; ++q) {                            \
      const int n = wv * 64 + q * 16 + cn;                                     \
      f32x2 w0 = *(const f32x2*)&wxb_s[0][n][0];                               \
      f32x2 w1 = *(const f32x2*)&wxb_s[1][n][0];                               \
      f32x2 b2 = *(const f32x2*)&wxb_s[2][n][0];                               \
      f32x2 lo = y01 * w1 + (x01 * w0 + b2);                                   \
      f32x2 hi = y23 * w1 + (x23 * w0 + b2);                                   \
      acc[q].x = lo.x;                                                         \
      acc[q].y = lo.y;                                                         \
      acc[q].z = hi.x;                                                         \
      acc[q].w = hi.y;                                                         \
    }                                                                          \
  } while (0)

// ---- main fused LSTM, R8 = R3 launch + R6 diet (correct placement) +
// s_setprio around the cell phase. 512 threads = 8 waves, wave wv owns ONE
// unit-group; batch/MB short-lived blocks, 2 blocks/CU = 4 waves/SIMD
// (R3/R5/R7 PROVEN: 2 co-resident blocks with independent barriers AND
// dispatcher-overlapped generations are both load-bearing).
// setprio(1) over the trans-heavy cell section: with two independent blocks
// per CU, priority makes whichever wave is in its cell chain win trans-pipe
// arbitration, finish sooner, and sleep at the barrier — a soft anti-phase
// forcing between the blocks (T5 regime: co-resident waves at different
// phases; the GEMM-lockstep null doesn't apply).
// Ledger (R1/R4 lesson): arch 56 (R6-measured) + 64 AGPR = 120 <= 128 cap.
// Tripwires: WRITE_SIZE exactly 32768 KB, FETCH ~38.5 MB, VGPR_Count <= 64.
__global__ __launch_bounds__(512, 4) void lstm_fused(
    const float* __restrict__ obs, const float* __restrict__ h0,
    const float* __restrict__ c0, const __bf16* __restrict__ Wp,
    const float* __restrict__ wxbp, float* __restrict__ out, int batch) {
  __shared__ __align__(16) __bf16 hbuf[2][MB][HSTR];
  __shared__ __align__(16) float obs_sx[OBS_T][MB];
  __shared__ __align__(16) float obs_sy[OBS_T][MB];
  __shared__ __align__(16) float wxb_s[3][NGATE][2];  // duplicated pairs

  const int tid = threadIdx.x;
  const int lane = tid & 63;
  const int wv = tid >> 6;  // 0..7 — unit-group index
  const int cn = lane & 15;
  const int quad = lane >> 4;
  const int bbase = blockIdx.x * MB;
  const int ju = wv * 16 + cn;  // this wave's output column

  // stage obs tile SoA: 320 float2 loads
  if (tid < OBS_T * MB) {
    const int t = tid >> 4, row = tid & 15;
    float2 v = ((const float2*)obs)[t * batch + bbase + row];
    obs_sx[t][row] = v.x;
    obs_sy[t][row] = v.y;
  }
  // stage duplicated wxb tables: 3 x 4 KB = 768 float4
  for (int i = tid; i < 768; i += 512)
    ((float4*)wxb_s)[i] = ((const float4*)wxbp)[i];
  // stage h0 tile fp32 -> bf16 LDS: 16 rows x 32 float4 = 512, one per thread
  {
    int row = tid >> 5, c4 = tid & 31;
    float4 v = ((const float4*)h0)[(bbase + row) * 32 + c4];
    bf16x4 b;
    b.x = (__bf16)v.x; b.y = (__bf16)v.y; b.z = (__bf16)v.z; b.w = (__bf16)v.w;
    *(bf16x4*)&hbuf[0][row][c4 * 4] = b;
  }

  // persistent B fragments: 1 unit-group x 4 gates x 4 ksteps = 64 regs (AGPR)
  bf16x8 Bf[4][4];  // [ks][q]
  {
    const bf16x8* wp8 = (const bf16x8*)Wp;
#pragma unroll
    for (int q = 0; q < 4; ++q)
#pragma unroll
      for (int ks = 0; ks < 4; ++ks)
        Bf[ks][q] = wp8[(wv * 16 + q * 4 + ks) * 64 + lane];
  }

  // c state as f32x2 pairs: cc2[p] = c for rows (quad*4+2p, quad*4+2p+1)
  f32x2 cc2[2];
#pragma unroll
  for (int p = 0; p < 2; ++p) {
    cc2[p].x = c0[(bbase + quad * 4 + 2 * p + 0) * HID + ju];
    cc2[p].y = c0[(bbase + quad * 4 + 2 * p + 1) * HID + ju];
  }

  __syncthreads();

  int cur = 0;
#pragma unroll 1
  for (int t = 0; t < OBS_T - 1; ++t) {
    // acc-init post-barrier (overlaps A-frag read latency)
    f32x4 acc[4];  // [q]
    ACC_INIT(t);

    // gates += h @ (scaled W_hh)^T : ONE A-load per ks, 16 MFMAs
#pragma unroll
    for (int ks = 0; ks < 4; ++ks) {
      bf16x8 Av = *(const bf16x8*)&hbuf[cur][cn][ks * 32 + quad * 8];
#pragma unroll
      for (int q = 0; q < 4; ++q)
        acc[q] = __builtin_amdgcn_mfma_f32_16x16x32_bf16(Av, Bf[ks][q], acc[q], 0, 0, 0);
    }

    // 4 cell updates as 2 packed pair-updates — setprio(1) makes the wave
    // currently in its trans chain win arbitration (anti-phase forcing).
    const int nxt = cur ^ 1;
    __builtin_amdgcn_s_setprio(1);
    {
      f32x2 hlo = cell_update_pk(acc[0].xy, acc[1].xy, acc[2].xy, acc[3].xy, cc2[0]);
      f32x2 hhi = cell_update_pk(acc[0].zw, acc[1].zw, acc[2].zw, acc[3].zw, cc2[1]);
      hbuf[nxt][quad * 4 + 0][ju] = (__bf16)hlo.x;
      hbuf[nxt][quad * 4 + 1][ju] = (__bf16)hlo.y;
      hbuf[nxt][quad * 4 + 2][ju] = (__bf16)hhi.x;
      hbuf[nxt][quad * 4 + 3][ju] = (__bf16)hhi.y;
    }
    __builtin_amdgcn_s_setprio(0);
    __syncthreads();
    cur = nxt;
  }

  // peeled final step (t=19): h straight to global
  {
    f32x4 acc[4];
    ACC_INIT(OBS_T - 1);
#pragma unroll
    for (int ks = 0; ks < 4; ++ks) {
      bf16x8 Av = *(const bf16x8*)&hbuf[cur][cn][ks * 32 + quad * 8];
#pragma unroll
      for (int q = 0; q < 4; ++q)
        acc[q] = __builtin_amdgcn_mfma_f32_16x16x32_bf16(Av, Bf[ks][q], acc[q], 0, 0, 0);
    }
    f32x2 hlo = cell_update_pk(acc[0].xy, acc[1].xy, acc[2].xy, acc[3].xy, cc2[0]);
    f32x2 hhi = cell_update_pk(acc[0].zw, acc[1].zw, acc[2].zw, acc[3].zw, cc2[1]);
    out[(bbase + quad * 4 + 0) * HID + ju] = hlo.x;
    out[(bbase + quad * 4 + 1) * HID + ju] = hlo.y;
    out[(bbase + quad * 4 + 2) * HID + ju] = hhi.x;
    out[(bbase + quad * 4 + 3) * HID + ju] = hhi.y;
  }
}

extern "C" void kernel_launch(void* const* d_in, const int* in_sizes, int n_in,
                              void* d_out, int out_size, void* d_ws, size_t ws_size,
                              hipStream_t stream) {
  const float* obs = (const float*)d_in[0];
  const float* h0 = (const float*)d_in[1];
  const float* c0 = (const float*)d_in[2];
  const float* W_emb = (const float*)d_in[3];
  const float* b_emb = (const float*)d_in[4];
  const float* W_ih = (const float*)d_in[5];
  const float* W_hh = (const float*)d_in[6];
  const float* b_ih = (const float*)d_in[7];
  const float* b_hh = (const float*)d_in[8];
  float* out = (float*)d_out;
  const int batch = in_sizes[1] / HID;

  __bf16* Wp = (__bf16*)d_ws;                      // 65536 bf16 = 128 KB
  float2* wxb = (float2*)((char*)d_ws + 131072);   // 3 x 512 duplicated f32 pairs = 12 KB

  prep_vec<<<2, 256, 0, stream>>>(W_emb, b_emb, W_ih, b_ih, b_hh, wxb);
  prep_wp<<<256, 256, 0, stream>>>(W_hh, Wp);
  lstm_fused<<<batch / MB, 512, 0, stream>>>(obs, h0, c0, Wp, (const float*)wxb, out, batch);
}